// Round 1
// baseline (306.983 us; speedup 1.0000x reference)
//
#include <hip/hip_runtime.h>
#include <math.h>

#define BB 32
#define NN 128
#define DD 64
#define EE (NN*NN)          // 16384
#define EPSI 1e-5f
#define CH 4                // edge channels per block in k_edge

// ---------------------------------------------------------------------------
// k_fold: M[d][k] = sum_o Wp[d][128+o] * We[o][k]   (fold fc_e into fc_proj)
//         w[k]    = sum_o Wa[128+o]    * We[o][k]   (fold fc_e into attn_fc)
// grid 16 x 256
__global__ void k_fold(const float* __restrict__ Wp, const float* __restrict__ We,
                       const float* __restrict__ Wa,
                       float* __restrict__ M, float* __restrict__ w)
{
    int t = blockIdx.x * 256 + threadIdx.x;   // 0..4095
    int d = t >> 6, k = t & 63;
    float acc = 0.f;
    for (int o = 0; o < DD; ++o)
        acc += Wp[d*192 + 128 + o] * We[o*DD + k];
    M[d*DD + k] = acc;
    if (d == 0) {
        float aw = 0.f;
        for (int o = 0; o < DD; ++o)
            aw += Wa[128 + o] * We[o*DD + k];
        w[k] = aw;
    }
}

// ---------------------------------------------------------------------------
// k_node: per (b,n) row: z_h = x @ Wh^T ; P_src = z_h @ Wp[:, :64]^T ;
//         P_dst = z_h @ Wp[:, 64:128]^T ; s = z_h . Wa[:64] ; t = z_h . Wa[64:128]
// grid B*N blocks x 64 threads (one wave)
__global__ void k_node(const float* __restrict__ x, const float* __restrict__ Wh,
                       const float* __restrict__ Wp, const float* __restrict__ Wa,
                       float* __restrict__ zh, float* __restrict__ Ps,
                       float* __restrict__ Pd, float* __restrict__ sO,
                       float* __restrict__ tO)
{
    int row = blockIdx.x;          // b*N + n
    int d = threadIdx.x;           // 0..63
    __shared__ float xr[DD];
    __shared__ float zr[DD];
    xr[d] = x[row*DD + d];
    __syncthreads();
    float acc = 0.f;
#pragma unroll
    for (int k = 0; k < DD; ++k) acc += xr[k] * Wh[d*DD + k];
    zr[d] = acc;
    zh[row*DD + d] = acc;
    __syncthreads();
    float a0 = 0.f, a1 = 0.f;
#pragma unroll
    for (int o = 0; o < DD; ++o) {
        float z = zr[o];
        a0 += Wp[d*192 + o]      * z;
        a1 += Wp[d*192 + 64 + o] * z;
    }
    Ps[row*DD + d] = a0;
    Pd[row*DD + d] = a1;
    float sv = zr[d] * Wa[d];
    float tv = zr[d] * Wa[64 + d];
#pragma unroll
    for (int off = 32; off; off >>= 1) {
        sv += __shfl_xor(sv, off);
        tv += __shfl_xor(tv, off);
    }
    if (d == 0) { sO[row] = sv; tO[row] = tv; }
}

// ---------------------------------------------------------------------------
// k_edge: fused  z = edge @ M^T + P_src[j] + P_dst[i]  ->  BN(per-e over b,d) -> ELU
//         side output u[b,e] = edge . w
// One block = CH e-channels x all B batches = 128 rows x 64 cols.
// 256 threads; thread (tr= t>>3, tc= t&7) computes 4 rows x 8 cols; wave == channel.
__global__ __launch_bounds__(256) void k_edge(
    const float* __restrict__ ein,   // (B,E,D)
    const float* __restrict__ M,     // (D,D)
    const float* __restrict__ wvec,  // (D)
    const float* __restrict__ Ps,    // (B,N,D)
    const float* __restrict__ Pd,    // (B,N,D)
    const float* __restrict__ ge, const float* __restrict__ be,
    float* __restrict__ eout, float* __restrict__ uout)
{
    __shared__ float A[128][68];   // A[r][k], r = e_local*32 + b (pad 68 vs bank conflicts)
    __shared__ float Bt[64][68];   // Bt[k][d] = M[d][k]
    const int t  = threadIdx.x;
    const int e0 = blockIdx.x * CH;

    // ---- stage Bt (transpose M) ----
    {
        int d = t >> 4;          // 0..15
        int q = t & 15;          // float4 index along k
        for (int dd = d; dd < 64; dd += 16) {
            const float4 mv = reinterpret_cast<const float4*>(M)[dd*16 + q];
            Bt[q*4+0][dd] = mv.x;
            Bt[q*4+1][dd] = mv.y;
            Bt[q*4+2][dd] = mv.z;
            Bt[q*4+3][dd] = mv.w;
        }
    }
    // ---- stage A (edge rows) + compute u on the fly ----
    {
        const int q = t & 15;
        const float4 wv = reinterpret_cast<const float4*>(wvec)[q];
#pragma unroll
        for (int p = 0; p < 8; ++p) {
            int r = (t >> 4) + p*16;            // 0..127
            int b = r & 31, e = e0 + (r >> 5);
            float4 v = reinterpret_cast<const float4*>(ein)[(b*EE + e)*16 + q];
            *reinterpret_cast<float4*>(&A[r][q*4]) = v;
            float up = v.x*wv.x + v.y*wv.y + v.z*wv.z + v.w*wv.w;
            up += __shfl_xor(up, 1);
            up += __shfl_xor(up, 2);
            up += __shfl_xor(up, 4);
            up += __shfl_xor(up, 8);
            if (q == 0) uout[b*EE + e] = up;
        }
    }
    __syncthreads();

    const int tr = t >> 3;        // 0..31 (row group: rows 4*tr .. 4*tr+3)
    const int tc = t & 7;         // 0..7  (cols 8*tc .. 8*tc+7)
    const int ch = tr >> 3;       // channel == wave id
    const int e  = e0 + ch;
    const int gi = e >> 7, gj = e & 127;

    float acc[4][8];
    // ---- init with P_src[b,j] + P_dst[b,i] ----
#pragma unroll
    for (int m = 0; m < 4; ++m) {
        int b = ((tr & 7) << 2) + m;
        const float4* ps = reinterpret_cast<const float4*>(Ps + (b*NN + gj)*DD + tc*8);
        const float4* pd = reinterpret_cast<const float4*>(Pd + (b*NN + gi)*DD + tc*8);
        float4 v0 = ps[0], v1 = ps[1];
        float4 w0 = pd[0], w1 = pd[1];
        acc[m][0] = v0.x + w0.x; acc[m][1] = v0.y + w0.y;
        acc[m][2] = v0.z + w0.z; acc[m][3] = v0.w + w0.w;
        acc[m][4] = v1.x + w1.x; acc[m][5] = v1.y + w1.y;
        acc[m][6] = v1.z + w1.z; acc[m][7] = v1.w + w1.w;
    }
    // ---- GEMM: acc += A_rows x Bt ----
#pragma unroll 4
    for (int k = 0; k < 64; ++k) {
        float a0 = A[tr*4+0][k];
        float a1 = A[tr*4+1][k];
        float a2 = A[tr*4+2][k];
        float a3 = A[tr*4+3][k];
        float4 b0 = *reinterpret_cast<const float4*>(&Bt[k][tc*8]);
        float4 b1 = *reinterpret_cast<const float4*>(&Bt[k][tc*8+4]);
        acc[0][0] += a0*b0.x; acc[0][1] += a0*b0.y; acc[0][2] += a0*b0.z; acc[0][3] += a0*b0.w;
        acc[0][4] += a0*b1.x; acc[0][5] += a0*b1.y; acc[0][6] += a0*b1.z; acc[0][7] += a0*b1.w;
        acc[1][0] += a1*b0.x; acc[1][1] += a1*b0.y; acc[1][2] += a1*b0.z; acc[1][3] += a1*b0.w;
        acc[1][4] += a1*b1.x; acc[1][5] += a1*b1.y; acc[1][6] += a1*b1.z; acc[1][7] += a1*b1.w;
        acc[2][0] += a2*b0.x; acc[2][1] += a2*b0.y; acc[2][2] += a2*b0.z; acc[2][3] += a2*b0.w;
        acc[2][4] += a2*b1.x; acc[2][5] += a2*b1.y; acc[2][6] += a2*b1.z; acc[2][7] += a2*b1.w;
        acc[3][0] += a3*b0.x; acc[3][1] += a3*b0.y; acc[3][2] += a3*b0.z; acc[3][3] += a3*b0.w;
        acc[3][4] += a3*b1.x; acc[3][5] += a3*b1.y; acc[3][6] += a3*b1.z; acc[3][7] += a3*b1.w;
    }
    // ---- BN stats: per-channel sum/sumsq over 2048 elems (one wave = one channel) ----
    float s1 = 0.f, s2 = 0.f;
#pragma unroll
    for (int m = 0; m < 4; ++m)
#pragma unroll
        for (int c = 0; c < 8; ++c) { float v = acc[m][c]; s1 += v; s2 += v*v; }
#pragma unroll
    for (int off = 1; off < 64; off <<= 1) {
        s1 += __shfl_xor(s1, off);
        s2 += __shfl_xor(s2, off);
    }
    float mean  = s1 * (1.f/2048.f);
    float var   = s2 * (1.f/2048.f) - mean*mean;
    float scale = ge[e] * rsqrtf(var + EPSI);
    float shift = be[e] - mean*scale;
    // ---- normalize + ELU + store ----
#pragma unroll
    for (int m = 0; m < 4; ++m) {
        int b = ((tr & 7) << 2) + m;
        float o[8];
#pragma unroll
        for (int c = 0; c < 8; ++c) {
            float v = acc[m][c]*scale + shift;
            o[c] = v > 0.f ? v : expm1f(v);
        }
        float4* dst = reinterpret_cast<float4*>(eout + (b*EE + e)*DD + tc*8);
        dst[0] = make_float4(o[0], o[1], o[2], o[3]);
        dst[1] = make_float4(o[4], o[5], o[6], o[7]);
    }
}

// ---------------------------------------------------------------------------
// k_attn: per (b,i): logits = lrelu(s[j] + t[i] + u[b,i*N+j]) -> softmax over j
//         agg[b,i,:] = sum_j attn_j * zh[b,j,:]
// grid B*N x 64 threads
__global__ void k_attn(const float* __restrict__ sI, const float* __restrict__ tI,
                       const float* __restrict__ u, const float* __restrict__ zh,
                       float* __restrict__ agg)
{
    int blk = blockIdx.x; int b = blk >> 7, i = blk & 127;
    int l = threadIdx.x;
    __shared__ float at[NN];
    float ti = tI[blk];
    float l0 = sI[b*NN + l]      + ti + u[b*EE + i*NN + l];
    float l1 = sI[b*NN + l + 64] + ti + u[b*EE + i*NN + l + 64];
    l0 = l0 >= 0.f ? l0 : 0.01f*l0;
    l1 = l1 >= 0.f ? l1 : 0.01f*l1;
    float mx = fmaxf(l0, l1);
#pragma unroll
    for (int off = 32; off; off >>= 1) mx = fmaxf(mx, __shfl_xor(mx, off));
    float e0 = expf(l0 - mx), e1 = expf(l1 - mx);
    float sm = e0 + e1;
#pragma unroll
    for (int off = 32; off; off >>= 1) sm += __shfl_xor(sm, off);
    float inv = 1.f / sm;
    at[l]      = e0 * inv;
    at[l + 64] = e1 * inv;
    __syncthreads();
    float acc = 0.f;
    for (int j = 0; j < NN; ++j) acc += at[j] * zh[(b*NN + j)*DD + l];
    agg[(b*NN + i)*DD + l] = acc;
}

// ---------------------------------------------------------------------------
// k_vbn: vertex BN (channel i over b,d) + residual + ELU
// grid N x 256
__global__ void k_vbn(const float* __restrict__ agg, const float* __restrict__ xres,
                      const float* __restrict__ gv, const float* __restrict__ bv,
                      float* __restrict__ xout)
{
    int i = blockIdx.x, t = threadIdx.x;
    float vals[8];
    float s1 = 0.f, s2 = 0.f;
#pragma unroll
    for (int q = 0; q < 8; ++q) {
        int m = t + 256*q; int b = m >> 6, d = m & 63;
        float v = agg[(b*NN + i)*DD + d];
        vals[q] = v; s1 += v; s2 += v*v;
    }
#pragma unroll
    for (int off = 1; off < 64; off <<= 1) {
        s1 += __shfl_xor(s1, off);
        s2 += __shfl_xor(s2, off);
    }
    __shared__ float r1[4], r2[4];
    int wv = t >> 6;
    if ((t & 63) == 0) { r1[wv] = s1; r2[wv] = s2; }
    __syncthreads();
    s1 = r1[0] + r1[1] + r1[2] + r1[3];
    s2 = r2[0] + r2[1] + r2[2] + r2[3];
    float mean  = s1 * (1.f/2048.f);
    float var   = s2 * (1.f/2048.f) - mean*mean;
    float scale = gv[i] * rsqrtf(var + EPSI);
    float shift = bv[i] - mean*scale;
#pragma unroll
    for (int q = 0; q < 8; ++q) {
        int m = t + 256*q; int b = m >> 6, d = m & 63;
        float v = vals[q]*scale + shift + xres[(b*NN + i)*DD + d];
        xout[(b*NN + i)*DD + d] = v > 0.f ? v : expm1f(v);
    }
}

// ---------------------------------------------------------------------------
extern "C" void kernel_launch(void* const* d_in, const int* in_sizes, int n_in,
                              void* d_out, int out_size, void* d_ws, size_t ws_size,
                              hipStream_t stream)
{
    const float* x    = (const float*)d_in[0];
    const float* edge = (const float*)d_in[1];
    const float* Wh1  = (const float*)d_in[2];
    const float* We1  = (const float*)d_in[3];
    const float* Wp1  = (const float*)d_in[4];
    const float* Wa1  = (const float*)d_in[5];
    const float* Wh2  = (const float*)d_in[6];
    const float* We2  = (const float*)d_in[7];
    const float* Wp2  = (const float*)d_in[8];
    const float* Wa2  = (const float*)d_in[9];
    const float* gv1  = (const float*)d_in[10];
    const float* bv1  = (const float*)d_in[11];
    const float* ge1  = (const float*)d_in[12];
    const float* be1  = (const float*)d_in[13];
    const float* gv2  = (const float*)d_in[14];
    const float* bv2  = (const float*)d_in[15];
    const float* ge2  = (const float*)d_in[16];
    const float* be2  = (const float*)d_in[17];

    float* xout = (float*)d_out;                    // (B,N,D)
    float* eout = (float*)d_out + BB*NN*DD;         // (B,E,D) — also layer-1 intermediate

    float* ws  = (float*)d_ws;
    float* M   = ws;  ws += DD*DD;
    float* wv  = ws;  ws += DD;
    float* zh  = ws;  ws += BB*NN*DD;
    float* Ps  = ws;  ws += BB*NN*DD;
    float* Pd  = ws;  ws += BB*NN*DD;
    float* sb  = ws;  ws += BB*NN;
    float* tb  = ws;  ws += BB*NN;
    float* ub  = ws;  ws += BB*EE;
    float* agg = ws;  ws += BB*NN*DD;
    float* x1  = ws;  ws += BB*NN*DD;   // total ~7.4 MB

    // ----- layer 1 -----
    k_fold<<<16, 256, 0, stream>>>(Wp1, We1, Wa1, M, wv);
    k_node<<<BB*NN, 64, 0, stream>>>(x, Wh1, Wp1, Wa1, zh, Ps, Pd, sb, tb);
    k_edge<<<EE/CH, 256, 0, stream>>>(edge, M, wv, Ps, Pd, ge1, be1, eout, ub);
    k_attn<<<BB*NN, 64, 0, stream>>>(sb, tb, ub, zh, agg);
    k_vbn<<<NN, 256, 0, stream>>>(agg, x, gv1, bv1, x1);
    // ----- layer 2 (edge path reads/writes eout in place; per-block rows staged first) -----
    k_fold<<<16, 256, 0, stream>>>(Wp2, We2, Wa2, M, wv);
    k_node<<<BB*NN, 64, 0, stream>>>(x1, Wh2, Wp2, Wa2, zh, Ps, Pd, sb, tb);
    k_edge<<<EE/CH, 256, 0, stream>>>(eout, M, wv, Ps, Pd, ge2, be2, eout, ub);
    k_attn<<<BB*NN, 64, 0, stream>>>(sb, tb, ub, zh, agg);
    k_vbn<<<NN, 256, 0, stream>>>(agg, x1, gv2, bv2, xout);
}